// Round 1
// baseline (681.893 us; speedup 1.0000x reference)
//
#include <hip/hip_runtime.h>

typedef _Float16 f16;
typedef _Float16 f16x8 __attribute__((ext_vector_type(8)));
typedef _Float16 f16x4 __attribute__((ext_vector_type(4)));
typedef float    f32x4 __attribute__((ext_vector_type(4)));

static constexpr int H  = 128;   // hidden width
static constexpr int MT = 128;   // edges per block
static constexpr int PC = 40;    // achunk/wchunk row stride in halves (32 + 8 pad)

// barrier that does NOT drain vmcnt: LDS writes visible, global loads stay in flight
__device__ __forceinline__ void wg_barrier() {
    asm volatile("s_waitcnt lgkmcnt(0)" ::: "memory");
    __builtin_amdgcn_s_barrier();
    asm volatile("" ::: "memory");
}

__global__ __launch_bounds__(256, 3)
void edge_mlp_fused(const float* __restrict__ x,
                    const int* __restrict__ eidx,     // int32 on device (harness contract)
                    const float* __restrict__ edge,
                    const float* __restrict__ W0, const float* __restrict__ b0,
                    const float* __restrict__ g0, const float* __restrict__ be0,
                    const float* __restrict__ W1, const float* __restrict__ b1,
                    const float* __restrict__ g1, const float* __restrict__ be1,
                    const float* __restrict__ W2, const float* __restrict__ b2,
                    const float* __restrict__ g2, const float* __restrict__ be2,
                    const float* __restrict__ W3, const float* __restrict__ b3,
                    float* __restrict__ out, int E)
{
    __shared__ __align__(16) f16 achunk[MT * PC];   // 10240 B
    __shared__ __align__(16) f16 wchunk[H * PC];    // 10240 B
    __shared__ __align__(16) f16 act[MT * H];       // 32768 B, XOR-swizzled, wave-private rows
    // total 53248 B -> 3 blocks/CU

    const int tid  = threadIdx.x;
    const int lane = tid & 63;
    const int wid  = tid >> 6;
    const int c    = lane & 15;   // MFMA "16-dim" lane coord
    const int g    = lane >> 4;   // quad group 0..3
    const int wrow = wid * 32;    // this wave's first local edge row
    const long long e0 = (long long)blockIdx.x * MT;

    // staging: thread owns row srow, half hf (fixed for whole kernel) -> pointers in regs
    const int srow = tid >> 1;
    const int hf   = tid & 1;
    long long er = e0 + srow; if (er >= E) er = (long long)E - 1;
    const float* psrc = x    + (size_t)eidx[er]     * H + hf * 16;
    const float* pdst = x    + (size_t)eidx[E + er] * H + hf * 16;
    const float* pedg = edge + (size_t)er           * H + hf * 16;

    f32x4 acc[8][2];
    #pragma unroll
    for (int t = 0; t < 8; ++t) {
        acc[t][0] = f32x4{0.f, 0.f, 0.f, 0.f};
        acc[t][1] = f32x4{0.f, 0.f, 0.f, 0.f};
    }

    // ---- prefetch registers (issue-early / write-late) ----
    float4 apf0, apf1, apf2, apf3;   // 64B of A row chunk
    float  wpf[16];                  // 16 strided W elements

    auto issueA = [&](int kc) {
        const float* b = (kc < 4) ? psrc : (kc < 8) ? pdst : pedg;
        const float4* p = (const float4*)(b + (kc & 3) * 32);
        apf0 = p[0]; apf1 = p[1]; apf2 = p[2]; apf3 = p[3];
    };
    auto writeA = [&]() {
        f16x8 lo, hi;
        lo[0] = (f16)apf0.x; lo[1] = (f16)apf0.y; lo[2] = (f16)apf0.z; lo[3] = (f16)apf0.w;
        lo[4] = (f16)apf1.x; lo[5] = (f16)apf1.y; lo[6] = (f16)apf1.z; lo[7] = (f16)apf1.w;
        hi[0] = (f16)apf2.x; hi[1] = (f16)apf2.y; hi[2] = (f16)apf2.z; hi[3] = (f16)apf2.w;
        hi[4] = (f16)apf3.x; hi[5] = (f16)apf3.y; hi[6] = (f16)apf3.z; hi[7] = (f16)apf3.w;
        *(f16x8*)&achunk[srow * PC + hf * 16]     = lo;
        *(f16x8*)&achunk[srow * PC + hf * 16 + 8] = hi;
    };
    auto issueW = [&](const float* __restrict__ W, int k0) {
        #pragma unroll
        for (int i = 0; i < 4; ++i) {
            int f  = i * 256 + tid;          // 0..1023 = 128 n x 8 kquads
            int n  = f & 127;
            int kq = f >> 7;                 // 0..7
            const float* p = W + (size_t)(k0 + kq * 4) * H + n;
            wpf[i * 4 + 0] = p[0];
            wpf[i * 4 + 1] = p[H];
            wpf[i * 4 + 2] = p[2 * H];
            wpf[i * 4 + 3] = p[3 * H];
        }
    };
    auto writeW = [&]() {
        #pragma unroll
        for (int i = 0; i < 4; ++i) {
            int f  = i * 256 + tid;
            int n  = f & 127;
            int kq = f >> 7;
            f16x4 v;
            v[0] = (f16)wpf[i * 4 + 0];
            v[1] = (f16)wpf[i * 4 + 1];
            v[2] = (f16)wpf[i * 4 + 2];
            v[3] = (f16)wpf[i * 4 + 3];
            *(f16x4*)&wchunk[n * PC + kq * 4] = v;   // 8B contiguous write
        }
    };

    // one K=32 step from achunk (padded layout)
    auto mfma_ach = [&]() {
        f16x8 a0 = *(const f16x8*)&achunk[(wrow + c)      * PC + g * 8];
        f16x8 a1 = *(const f16x8*)&achunk[(wrow + 16 + c) * PC + g * 8];
        #pragma unroll
        for (int t = 0; t < 8; ++t) {
            f16x8 bf = *(const f16x8*)&wchunk[(t * 16 + c) * PC + g * 8];
            acc[t][0] = __builtin_amdgcn_mfma_f32_16x16x32_f16(a0, bf, acc[t][0], 0, 0, 0);
            acc[t][1] = __builtin_amdgcn_mfma_f32_16x16x32_f16(a1, bf, acc[t][1], 0, 0, 0);
        }
    };
    // one K=32 step from act (swizzled layout); rows wrow..wrow+31 are wave-private
    auto mfma_act = [&](int koff) {
        int col = (koff + g * 8) ^ ((c & 7) << 3);
        f16x8 a0 = *(const f16x8*)&act[(wrow + c)      * H + col];
        f16x8 a1 = *(const f16x8*)&act[(wrow + 16 + c) * H + col];
        #pragma unroll
        for (int t = 0; t < 8; ++t) {
            f16x8 bf = *(const f16x8*)&wchunk[(t * 16 + c) * PC + g * 8];
            acc[t][0] = __builtin_amdgcn_mfma_f32_16x16x32_f16(a0, bf, acc[t][0], 0, 0, 0);
            acc[t][1] = __builtin_amdgcn_mfma_f32_16x16x32_f16(a1, bf, acc[t][1], 0, 0, 0);
        }
    };

    // LayerNorm(+bias,gamma,beta)+ReLU on acc, write f16 act (swizzled), reset acc.
    // act rows are wave-private -> no barrier needed here.
    auto ln_relu_store = [&](const float* __restrict__ bias,
                             const float* __restrict__ gamma,
                             const float* __restrict__ beta) {
        float mu[2][4], rs[2][4];
        #pragma unroll
        for (int t = 0; t < 8; ++t) {
            float bt = bias[t * 16 + c];
            #pragma unroll
            for (int s = 0; s < 2; ++s)
                #pragma unroll
                for (int r = 0; r < 4; ++r) acc[t][s][r] += bt;
        }
        #pragma unroll
        for (int s = 0; s < 2; ++s)
            #pragma unroll
            for (int r = 0; r < 4; ++r) {
                float v = 0.f, q = 0.f;
                #pragma unroll
                for (int t = 0; t < 8; ++t) { float a = acc[t][s][r]; v += a; q += a * a; }
                #pragma unroll
                for (int m = 1; m < 16; m <<= 1) {
                    v += __shfl_xor(v, m, 64);
                    q += __shfl_xor(q, m, 64);
                }
                float mean = v * (1.0f / H);
                float var  = q * (1.0f / H) - mean * mean;
                mu[s][r] = mean;
                rs[s][r] = rsqrtf(var + 1e-5f);
            }
        #pragma unroll
        for (int t = 0; t < 8; ++t) {
            float gm = gamma[t * 16 + c];
            float bb = beta[t * 16 + c];
            #pragma unroll
            for (int s = 0; s < 2; ++s)
                #pragma unroll
                for (int r = 0; r < 4; ++r) {
                    float v = (acc[t][s][r] - mu[s][r]) * rs[s][r] * gm + bb;
                    v = fmaxf(v, 0.f);
                    int row = wrow + s * 16 + g * 4 + r;
                    act[row * H + ((t * 16 + c) ^ ((row & 7) << 3))] = (f16)v;
                }
        }
        #pragma unroll
        for (int t = 0; t < 8; ++t) {
            acc[t][0] = f32x4{0.f, 0.f, 0.f, 0.f};
            acc[t][1] = f32x4{0.f, 0.f, 0.f, 0.f};
        }
    };

    // ---------------- GEMM1: concat(x[src],x[dst],edge) @ W0, K=384 ----------------
    issueA(0);
    issueW(W0, 0);
    #pragma unroll 1
    for (int kc = 0; kc < 12; ++kc) {
        wg_barrier();                  // previous chunk's LDS readers done
        writeA();                      // waits vmcnt for its own regs only
        writeW();
        if (kc < 11) { issueA(kc + 1); issueW(W0, (kc + 1) * 32); }
        else         { issueW(W1, 0); }   // pre-issue GEMM2's first W chunk
        wg_barrier();                  // staged chunk visible
        mfma_ach();
    }
    ln_relu_store(b0, g0, be0);

    // ---------------- GEMM2: act @ W1, K=128 ----------------
    #pragma unroll 1
    for (int kc = 0; kc < 4; ++kc) {
        wg_barrier();                  // prev mfma's wchunk readers done (+ act writes visible)
        writeW();
        if (kc < 3) issueW(W1, (kc + 1) * 32);
        else        issueW(W2, 0);
        wg_barrier();
        mfma_act(kc * 32);
    }
    ln_relu_store(b1, g1, be1);

    // ---------------- GEMM3: act @ W2, K=128 ----------------
    #pragma unroll 1
    for (int kc = 0; kc < 4; ++kc) {
        wg_barrier();
        writeW();
        if (kc < 3) issueW(W2, (kc + 1) * 32);
        wg_barrier();
        mfma_act(kc * 32);
    }

    // ---------------- layer-3 LN+ReLU fused with final dot(W3)+b3 ----------------
    {
        float mu[2][4], rs[2][4];
        #pragma unroll
        for (int t = 0; t < 8; ++t) {
            float bt = b2[t * 16 + c];
            #pragma unroll
            for (int s = 0; s < 2; ++s)
                #pragma unroll
                for (int r = 0; r < 4; ++r) acc[t][s][r] += bt;
        }
        #pragma unroll
        for (int s = 0; s < 2; ++s)
            #pragma unroll
            for (int r = 0; r < 4; ++r) {
                float v = 0.f, q = 0.f;
                #pragma unroll
                for (int t = 0; t < 8; ++t) { float a = acc[t][s][r]; v += a; q += a * a; }
                #pragma unroll
                for (int m = 1; m < 16; m <<= 1) {
                    v += __shfl_xor(v, m, 64);
                    q += __shfl_xor(q, m, 64);
                }
                float mean = v * (1.0f / H);
                float var  = q * (1.0f / H) - mean * mean;
                mu[s][r] = mean;
                rs[s][r] = rsqrtf(var + 1e-5f);
            }
        float po[2][4] = {{0.f,0.f,0.f,0.f},{0.f,0.f,0.f,0.f}};
        #pragma unroll
        for (int t = 0; t < 8; ++t) {
            float gm  = g2[t * 16 + c];
            float bb  = be2[t * 16 + c];
            float w3v = W3[t * 16 + c];
            #pragma unroll
            for (int s = 0; s < 2; ++s)
                #pragma unroll
                for (int r = 0; r < 4; ++r) {
                    float v = (acc[t][s][r] - mu[s][r]) * rs[s][r] * gm + bb;
                    v = fmaxf(v, 0.f);
                    po[s][r] += v * w3v;
                }
        }
        #pragma unroll
        for (int s = 0; s < 2; ++s)
            #pragma unroll
            for (int r = 0; r < 4; ++r) {
                #pragma unroll
                for (int m = 1; m < 16; m <<= 1) po[s][r] += __shfl_xor(po[s][r], m, 64);
            }
        if (c == 0) {
            float bb3 = b3[0];
            #pragma unroll
            for (int s = 0; s < 2; ++s) {
                long long eb = e0 + wrow + s * 16 + g * 4;
                if (eb + 3 < E) {
                    float4 o;
                    o.x = po[s][0] + bb3; o.y = po[s][1] + bb3;
                    o.z = po[s][2] + bb3; o.w = po[s][3] + bb3;
                    *(float4*)(out + eb) = o;
                } else {
                    #pragma unroll
                    for (int r = 0; r < 4; ++r)
                        if (eb + r < E) out[eb + r] = po[s][r] + bb3;
                }
            }
        }
    }
}

extern "C" void kernel_launch(void* const* d_in, const int* in_sizes, int n_in,
                              void* d_out, int out_size, void* d_ws, size_t ws_size,
                              hipStream_t stream)
{
    const float* x    = (const float*)d_in[0];
    const int*   eidx = (const int*)d_in[1];     // int64 in reference -> int32 on device
    const float* edge = (const float*)d_in[2];
    const float* W0   = (const float*)d_in[3];
    const float* b0   = (const float*)d_in[4];
    const float* g0   = (const float*)d_in[5];
    const float* be0  = (const float*)d_in[6];
    const float* W1   = (const float*)d_in[7];
    const float* b1   = (const float*)d_in[8];
    const float* g1   = (const float*)d_in[9];
    const float* be1  = (const float*)d_in[10];
    const float* W2   = (const float*)d_in[11];
    const float* b2   = (const float*)d_in[12];
    const float* g2   = (const float*)d_in[13];
    const float* be2  = (const float*)d_in[14];
    const float* W3   = (const float*)d_in[15];
    const float* b3   = (const float*)d_in[16];
    float*       out  = (float*)d_out;

    const int E = in_sizes[1] / 2;           // edge_index is (2, E)
    const int grid = (E + MT - 1) / MT;

    hipLaunchKernelGGL(edge_mlp_fused, dim3(grid), dim3(256), 0, stream,
                       x, eidx, edge,
                       W0, b0, g0, be0,
                       W1, b1, g1, be1,
                       W2, b2, g2, be2,
                       W3, b3, out, E);
}

// Round 3
// 603.665 us; speedup vs baseline: 1.1296x; 1.1296x over previous
//
#include <hip/hip_runtime.h>

typedef _Float16 f16;
typedef _Float16 f16x8 __attribute__((ext_vector_type(8)));
typedef _Float16 f16x4 __attribute__((ext_vector_type(4)));
typedef float    f32x4 __attribute__((ext_vector_type(4)));

static constexpr int H   = 128;   // hidden width
static constexpr int MT  = 128;   // edges per block
static constexpr int WCH = 4096;  // halves per W chunk (128 n x 32 k)
static constexpr int NCH = 20;    // 12 (W0) + 4 (W1) + 4 (W2)
static constexpr size_t WS_NEED = (size_t)NCH * WCH * sizeof(f16);  // 163840 B

// -------- W pre-conversion: f32 row-major [K][128] -> f16 swizzled chunk image --------
// element (n, k) of chunk cid lives at ws[cid*4096 + n*32 + ((k>>3) ^ ((n>>2)&3))*8 + (k&7)]
__global__ __launch_bounds__(256)
void wprep(const float* __restrict__ W0, const float* __restrict__ W1,
           const float* __restrict__ W2, f16* __restrict__ ws)
{
    int e = blockIdx.x * 256 + threadIdx.x;
    if (e >= NCH * WCH) return;
    int cid = e >> 12;
    int rem = e & 4095;
    int k   = rem >> 7;     // 0..31
    int n   = rem & 127;    // fastest -> coalesced W reads
    const float* W; int k0;
    if (cid < 12)      { W = W0; k0 = cid * 32; }
    else if (cid < 16) { W = W1; k0 = (cid - 12) * 32; }
    else               { W = W2; k0 = (cid - 16) * 32; }
    f16 v = (f16)W[(size_t)(k0 + k) * H + n];
    int su = (k >> 3) ^ ((n >> 2) & 3);
    ws[cid * WCH + n * 32 + su * 8 + (k & 7)] = v;
}

__device__ __forceinline__ void glds16(const f16* g, f16* l) {
    __builtin_amdgcn_global_load_lds((const __attribute__((address_space(1))) void*)g,
                                     (__attribute__((address_space(3))) void*)l, 16, 0, 0);
}

template <int WPRE>
__global__ __launch_bounds__(256, 3)
void edge_mlp_fused(const float* __restrict__ x,
                    const int* __restrict__ eidx,
                    const float* __restrict__ edge,
                    const f16* __restrict__ wpre,
                    const float* __restrict__ W0, const float* __restrict__ b0,
                    const float* __restrict__ g0, const float* __restrict__ be0,
                    const float* __restrict__ W1, const float* __restrict__ b1,
                    const float* __restrict__ g1, const float* __restrict__ be1,
                    const float* __restrict__ W2, const float* __restrict__ b2,
                    const float* __restrict__ g2, const float* __restrict__ be2,
                    const float* __restrict__ W3, const float* __restrict__ b3,
                    float* __restrict__ out, int E)
{
    // double-buffered W tile: 128 n x 32 k halves each, swizzled
    __shared__ __align__(16) f16 wch[2 * WCH];    // 16384 B
    // union: GEMM1 per-wave A slices (4 x 1024 halves) / act (128 x 128 halves)
    __shared__ __align__(16) f16 uni[MT * H];     // 32768 B
    // total 49152 B -> 3 blocks/CU

    const int tid  = threadIdx.x;
    const int lane = tid & 63;
    const int wid  = tid >> 6;
    const int c    = lane & 15;   // MFMA 16-dim lane coord
    const int g    = lane >> 4;   // quad group 0..3
    const int wrow = wid * 32;
    const long long e0 = (long long)blockIdx.x * MT;

    // A staging: lane -> (row r_ within wave tile, half hf)
    const int r_ = lane >> 1;
    const int hf = lane & 1;
    long long er = e0 + wrow + r_; if (er >= E) er = (long long)E - 1;
    const float* psrc = x    + (size_t)eidx[er]     * H;
    const float* pdst = x    + (size_t)eidx[E + er] * H;
    const float* pedg = edge + (size_t)er           * H;

    f16* aslice = &uni[wid * 1024];                   // wave-private 32x32 halves
    const int s_    = (r_ >> 2) & 3;
    const int aoff0 = r_ * 32 + ((2 * hf)     ^ s_) * 8;
    const int aoff1 = r_ * 32 + ((2 * hf + 1) ^ s_) * 8;
    const int sw    = (g ^ ((c >> 2) & 3)) * 8;       // read-side swizzle (halves)

    f32x4 acc[8][2];
    #pragma unroll
    for (int t = 0; t < 8; ++t) {
        acc[t][0] = f32x4{0.f, 0.f, 0.f, 0.f};
        acc[t][1] = f32x4{0.f, 0.f, 0.f, 0.f};
    }

    // ---- depth-1 A prefetch (16 VGPR) ----
    float4 apf0, apf1, apf2, apf3;
    auto issueA = [&](int kc) {
        const float* bptr = (kc < 4) ? psrc : (kc < 8) ? pdst : pedg;
        const float4* p = (const float4*)(bptr + (kc & 3) * 32 + hf * 16);
        apf0 = p[0]; apf1 = p[1]; apf2 = p[2]; apf3 = p[3];
    };
    auto writeA = [&]() {
        f16x8 lo, hi;
        lo[0] = (f16)apf0.x; lo[1] = (f16)apf0.y; lo[2] = (f16)apf0.z; lo[3] = (f16)apf0.w;
        lo[4] = (f16)apf1.x; lo[5] = (f16)apf1.y; lo[6] = (f16)apf1.z; lo[7] = (f16)apf1.w;
        hi[0] = (f16)apf2.x; hi[1] = (f16)apf2.y; hi[2] = (f16)apf2.z; hi[3] = (f16)apf2.w;
        hi[4] = (f16)apf3.x; hi[5] = (f16)apf3.y; hi[6] = (f16)apf3.z; hi[7] = (f16)apf3.w;
        *(f16x8*)&aslice[aoff0] = lo;
        *(f16x8*)&aslice[aoff1] = hi;
    };

    // stage W chunk cid into wchunk buffer pbuf (visible after next __syncthreads)
    auto stageW = [&](int cid, int pbuf) {
        f16* dst = &wch[pbuf * WCH];
        if (WPRE) {
            const f16* src = wpre + (size_t)cid * WCH + wid * 1024;  // wave covers 2 KB
            f16* d = dst + wid * 1024;                               // wave-uniform LDS base
            glds16(src + (lane << 3), d);                            // lanes fill d + lane*16B
            glds16(src + 512 + (lane << 3), d + 512);
        } else {
            const float* W = (cid < 12) ? W0 : (cid < 16) ? W1 : W2;
            int k0 = ((cid < 12) ? cid : (cid < 16) ? (cid - 12) : (cid - 16)) * 32;
            #pragma unroll
            for (int i = 0; i < 4; ++i) {
                int f  = i * 256 + tid;
                int n  = f & 127;
                int kq = f >> 7;   // 0..7
                const float* pw = W + (size_t)(k0 + kq * 4) * H + n;
                f16x4 v;
                v[0] = (f16)pw[0]; v[1] = (f16)pw[H]; v[2] = (f16)pw[2 * H]; v[3] = (f16)pw[3 * H];
                int su = (kq >> 1) ^ ((n >> 2) & 3);
                *(f16x4*)&dst[n * 32 + su * 8 + (kq & 1) * 4] = v;
            }
        }
    };

    auto mfma_ach = [&](int pbuf) {
        const f16* wb = &wch[pbuf * WCH];
        f16x8 a0 = *(const f16x8*)&aslice[c * 32 + sw];          // swizzle idx same for c, c+16
        f16x8 a1 = *(const f16x8*)&aslice[(16 + c) * 32 + sw];
        #pragma unroll
        for (int t = 0; t < 8; ++t) {
            f16x8 bf = *(const f16x8*)&wb[(t * 16 + c) * 32 + sw];
            acc[t][0] = __builtin_amdgcn_mfma_f32_16x16x32_f16(a0, bf, acc[t][0], 0, 0, 0);
            acc[t][1] = __builtin_amdgcn_mfma_f32_16x16x32_f16(a1, bf, acc[t][1], 0, 0, 0);
        }
    };
    auto mfma_act = [&](int koff, int pbuf) {
        const f16* wb = &wch[pbuf * WCH];
        int col = (koff + g * 8) ^ ((c & 7) << 3);
        f16x8 a0 = *(const f16x8*)&uni[(wrow + c) * H + col];
        f16x8 a1 = *(const f16x8*)&uni[(wrow + 16 + c) * H + col];
        #pragma unroll
        for (int t = 0; t < 8; ++t) {
            f16x8 bf = *(const f16x8*)&wb[(t * 16 + c) * 32 + sw];
            acc[t][0] = __builtin_amdgcn_mfma_f32_16x16x32_f16(a0, bf, acc[t][0], 0, 0, 0);
            acc[t][1] = __builtin_amdgcn_mfma_f32_16x16x32_f16(a1, bf, acc[t][1], 0, 0, 0);
        }
    };

    // LN(+bias,gamma,beta)+ReLU on acc -> act (swizzled rows, wave-private), reset acc
    auto ln_relu_store = [&](const float* __restrict__ bias,
                             const float* __restrict__ gamma,
                             const float* __restrict__ beta) {
        float mu[2][4], rs[2][4];
        #pragma unroll
        for (int t = 0; t < 8; ++t) {
            float bt = bias[t * 16 + c];
            #pragma unroll
            for (int s = 0; s < 2; ++s)
                #pragma unroll
                for (int r = 0; r < 4; ++r) acc[t][s][r] += bt;
        }
        #pragma unroll
        for (int s = 0; s < 2; ++s)
            #pragma unroll
            for (int r = 0; r < 4; ++r) {
                float v = 0.f, q = 0.f;
                #pragma unroll
                for (int t = 0; t < 8; ++t) { float a = acc[t][s][r]; v += a; q += a * a; }
                #pragma unroll
                for (int m = 1; m < 16; m <<= 1) {
                    v += __shfl_xor(v, m, 64);
                    q += __shfl_xor(q, m, 64);
                }
                float mean = v * (1.0f / H);
                float var  = q * (1.0f / H) - mean * mean;
                mu[s][r] = mean;
                rs[s][r] = rsqrtf(var + 1e-5f);
            }
        #pragma unroll
        for (int t = 0; t < 8; ++t) {
            float gm = gamma[t * 16 + c];
            float bb = beta[t * 16 + c];
            #pragma unroll
            for (int s = 0; s < 2; ++s)
                #pragma unroll
                for (int r = 0; r < 4; ++r) {
                    float v = (acc[t][s][r] - mu[s][r]) * rs[s][r] * gm + bb;
                    v = fmaxf(v, 0.f);
                    int row = wrow + s * 16 + g * 4 + r;
                    uni[row * H + ((t * 16 + c) ^ ((row & 7) << 3))] = (f16)v;
                }
        }
        #pragma unroll
        for (int t = 0; t < 8; ++t) {
            acc[t][0] = f32x4{0.f, 0.f, 0.f, 0.f};
            acc[t][1] = f32x4{0.f, 0.f, 0.f, 0.f};
        }
    };

    // ---------------- prologue ----------------
    stageW(0, 0);
    issueA(0);
    __syncthreads();   // W chunk 0 visible (A(0) completes too; value kept in regs)

    // ---------------- GEMM1: concat(x[src],x[dst],edge) @ W0, K=384 ----------------
    #pragma unroll 2
    for (int kc = 0; kc < 12; ++kc) {
        stageW(kc + 1, (kc + 1) & 1);   // kc==11 pre-stages W1 chunk 0 (cid 12)
        writeA();                        // consume prefetched A into wave-private slice
        if (kc < 11) issueA(kc + 1);
        mfma_ach(kc & 1);
        __syncthreads();                 // staged chunk visible; read buffer retired
    }
    ln_relu_store(b0, g0, be0);          // aslice readers all done at last barrier

    // ---------------- GEMM2: act @ W1, K=128 ----------------
    #pragma unroll 2
    for (int kc = 0; kc < 4; ++kc) {
        stageW(13 + kc, (kc + 1) & 1);   // W1 chunks 1..3, then W2 chunk 0 (cid 16)
        mfma_act(kc * 32, kc & 1);
        __syncthreads();
    }
    ln_relu_store(b1, g1, be1);

    // ---------------- GEMM3: act @ W2, K=128 ----------------
    #pragma unroll 2
    for (int kc = 0; kc < 4; ++kc) {
        if (kc < 3) stageW(17 + kc, (kc + 1) & 1);
        mfma_act(kc * 32, kc & 1);
        if (kc < 3) __syncthreads();
    }

    // ---------------- layer-3 LN+ReLU fused with final dot(W3)+b3 ----------------
    {
        float mu[2][4], rs[2][4];
        #pragma unroll
        for (int t = 0; t < 8; ++t) {
            float bt = b2[t * 16 + c];
            #pragma unroll
            for (int s = 0; s < 2; ++s)
                #pragma unroll
                for (int r = 0; r < 4; ++r) acc[t][s][r] += bt;
        }
        #pragma unroll
        for (int s = 0; s < 2; ++s)
            #pragma unroll
            for (int r = 0; r < 4; ++r) {
                float v = 0.f, q = 0.f;
                #pragma unroll
                for (int t = 0; t < 8; ++t) { float a = acc[t][s][r]; v += a; q += a * a; }
                #pragma unroll
                for (int m = 1; m < 16; m <<= 1) {
                    v += __shfl_xor(v, m, 64);
                    q += __shfl_xor(q, m, 64);
                }
                float mean = v * (1.0f / H);
                float var  = q * (1.0f / H) - mean * mean;
                mu[s][r] = mean;
                rs[s][r] = rsqrtf(var + 1e-5f);
            }
        float po[2][4] = {{0.f,0.f,0.f,0.f},{0.f,0.f,0.f,0.f}};
        #pragma unroll
        for (int t = 0; t < 8; ++t) {
            float gm  = g2[t * 16 + c];
            float bb  = be2[t * 16 + c];
            float w3v = W3[t * 16 + c];
            #pragma unroll
            for (int s = 0; s < 2; ++s)
                #pragma unroll
                for (int r = 0; r < 4; ++r) {
                    float v = (acc[t][s][r] - mu[s][r]) * rs[s][r] * gm + bb;
                    v = fmaxf(v, 0.f);
                    po[s][r] += v * w3v;
                }
        }
        #pragma unroll
        for (int s = 0; s < 2; ++s)
            #pragma unroll
            for (int r = 0; r < 4; ++r) {
                #pragma unroll
                for (int m = 1; m < 16; m <<= 1) po[s][r] += __shfl_xor(po[s][r], m, 64);
            }
        if (c == 0) {
            float bb3 = b3[0];
            #pragma unroll
            for (int s = 0; s < 2; ++s) {
                long long eb = e0 + wrow + s * 16 + g * 4;
                if (eb + 3 < E) {
                    float4 o;
                    o.x = po[s][0] + bb3; o.y = po[s][1] + bb3;
                    o.z = po[s][2] + bb3; o.w = po[s][3] + bb3;
                    *(float4*)(out + eb) = o;
                } else {
                    #pragma unroll
                    for (int r = 0; r < 4; ++r)
                        if (eb + r < E) out[eb + r] = po[s][r] + bb3;
                }
            }
        }
    }
}

extern "C" void kernel_launch(void* const* d_in, const int* in_sizes, int n_in,
                              void* d_out, int out_size, void* d_ws, size_t ws_size,
                              hipStream_t stream)
{
    const float* x    = (const float*)d_in[0];
    const int*   eidx = (const int*)d_in[1];     // int64 in reference -> int32 on device
    const float* edge = (const float*)d_in[2];
    const float* W0   = (const float*)d_in[3];
    const float* b0   = (const float*)d_in[4];
    const float* g0   = (const float*)d_in[5];
    const float* be0  = (const float*)d_in[6];
    const float* W1   = (const float*)d_in[7];
    const float* b1   = (const float*)d_in[8];
    const float* g1   = (const float*)d_in[9];
    const float* be1  = (const float*)d_in[10];
    const float* W2   = (const float*)d_in[11];
    const float* b2   = (const float*)d_in[12];
    const float* g2   = (const float*)d_in[13];
    const float* be2  = (const float*)d_in[14];
    const float* W3   = (const float*)d_in[15];
    const float* b3   = (const float*)d_in[16];
    float*       out  = (float*)d_out;

    const int E = in_sizes[1] / 2;           // edge_index is (2, E)
    const int grid = (E + MT - 1) / MT;

    if (d_ws && ws_size >= WS_NEED) {
        f16* wsp = (f16*)d_ws;
        hipLaunchKernelGGL(wprep, dim3((NCH * WCH + 255) / 256), dim3(256), 0, stream,
                           W0, W1, W2, wsp);
        hipLaunchKernelGGL((edge_mlp_fused<1>), dim3(grid), dim3(256), 0, stream,
                           x, eidx, edge, (const f16*)wsp,
                           W0, b0, g0, be0, W1, b1, g1, be1, W2, b2, g2, be2,
                           W3, b3, out, E);
    } else {
        hipLaunchKernelGGL((edge_mlp_fused<0>), dim3(grid), dim3(256), 0, stream,
                           x, eidx, edge, (const f16*)nullptr,
                           W0, b0, g0, be0, W1, b1, g1, be1, W2, b2, g2, be2,
                           W3, b3, out, E);
    }
}